// Round 20
// baseline (298.697 us; speedup 1.0000x reference)
//
#include <hip/hip_runtime.h>

// B=8, C=384, 96x96 stride-2 -> 48x48, N=2304 tokens.
// qkv = W(1152x384) @ xs(384xN); 6 heads x (q,k,v) of 64 dims.
// attn = softmax(q^T k); out[d][n] = sum_m v[d][m] P[n][m].
// Single-fp16 MFMA pipeline, offset-free exp2 softmax.
// Attention: 128 queries/block as two 64-query tiles; K fragments hoisted
// into registers once per KV tile (reused by both q-tiles); V read from
// LDS per tile.  __launch_bounds__(256,4): 4 blocks/CU so the whole 864-
// block grid is co-resident in ONE dispatch wave (round 19's (256,3) left
// a 12% tail).  Memory fence between P-pack writes and P-fragment reads.

#define NTOK 2304
#define NB 8
#define W_U16 (1152 * 384)             // W fp16 plane (single)
#define XT_U16 (NTOK * 384)            // xsT fp16 plane (single)
#define PLANE_U16 (NTOK * 64)          // one qkv fp16 plane (147456)
#define KVTILE_U16 8192                // Kh(4096) + V(4096) per 64-key tile
#define HEAD_U16 (PLANE_U16 + 36 * KVTILE_U16)   // Qh + 36 KV tiles
#define SLOT_U16 (XT_U16 + 6 * HEAD_U16)
#define SLOT_BYTES ((size_t)SLOT_U16 * 2)   // 7.08 MB / batch
#define WBYTES ((size_t)W_U16 * 2)          // 0.88 MB
#define LOG2E 1.4426950408889634f
#define WSCALE 1024.0f
#define WS_INV (1.0f / 1024.0f)

typedef __attribute__((ext_vector_type(8))) _Float16 f16x8;
typedef __attribute__((ext_vector_type(4))) float f32x4;

__device__ __forceinline__ ushort f2h(float f) {
  union { _Float16 h; ushort u; } v; v.h = (_Float16)f; return v.u;
}
__device__ __forceinline__ uint cvt_pk_f16(float lo, float hi) {
  uint r;
  asm("v_cvt_pkrtz_f16_f32 %0, %1, %2" : "=v"(r) : "v"(lo), "v"(hi));
  return r;
}
__device__ __forceinline__ float exp2_fast(float x) {
  float r;
  asm("v_exp_f32 %0, %1" : "=v"(r) : "v"(x));
  return r;
}

// ---------------------------------------------------------------------------
// Kernel W: 1024*W -> single fp16 plane; q-rows also carry log2(e).
// ---------------------------------------------------------------------------
__global__ __launch_bounds__(256) void prep_w_kernel(
    const float* __restrict__ w, ushort* __restrict__ wsu) {
  const int idx4 = blockIdx.x * 256 + threadIdx.x;  // 110592 total
  const int o = idx4 / 96;                          // W row
  const float scale = (((o % 192) < 64) ? LOG2E : 1.0f) * WSCALE;
  float4 v = *(const float4*)&w[(size_t)idx4 * 4];
  uint2 uh;
  uh.x = (uint)f2h(v.x * scale) | ((uint)f2h(v.y * scale) << 16);
  uh.y = (uint)f2h(v.z * scale) | ((uint)f2h(v.w * scale) << 16);
  *(uint2*)&wsu[(size_t)idx4 * 4] = uh;
}

// ---------------------------------------------------------------------------
// Kernel X: subsample + transpose x -> xsT[n][c] single fp16 plane.
// ---------------------------------------------------------------------------
__global__ __launch_bounds__(256) void prep_x_kernel(
    const float* __restrict__ x, ushort* __restrict__ wsu, int b0) {
  const int hh = blockIdx.x, cc = blockIdx.y, bb = blockIdx.z;
  const int b = b0 + bb;
  const int c0 = cc * 64;
  ushort* xth = wsu + (size_t)W_U16 + (size_t)bb * SLOT_U16;
  const float* xb = x + ((size_t)b * 384 + c0) * 9216 + 192 * hh;

  __shared__ float T[64][49];
  const int tid = threadIdx.x;
#pragma unroll
  for (int i = 0; i < 8; ++i) {
    int idx = tid + 256 * i;
    int cl = idx >> 5, q = idx & 31;
    if (q < 24) {
      float4 v = *(const float4*)&xb[(size_t)cl * 9216 + 4 * q];
      T[cl][2 * q] = v.x;
      T[cl][2 * q + 1] = v.z;
    }
  }
  __syncthreads();
#pragma unroll
  for (int i = 0; i < 2; ++i) {
    int item = tid + 256 * i;
    if (item < 384) {
      int ww = item >> 3, cg = item & 7;
      int n = hh * 48 + ww;
      uint uh[4];
#pragma unroll
      for (int p = 0; p < 4; ++p) {
        float f0 = T[8 * cg + 2 * p][ww], f1 = T[8 * cg + 2 * p + 1][ww];
        uh[p] = (uint)f2h(f0) | ((uint)f2h(f1) << 16);
      }
      uint4 H = {uh[0], uh[1], uh[2], uh[3]};
      *(uint4*)&xth[(size_t)n * 384 + c0 + 8 * cg] = H;
    }
  }
}

// ---------------------------------------------------------------------------
// Kernel G: single-fp16 MFMA projection GEMM (8 MFMA/K-step), reg-prefetch
// + double-buffered LDS (one barrier per K-step).  Epilogue (acc * 1/1024)
// writes attention-ready layouts:
//  t=0 (q): [n][64] fp16 plane
//  t=1 (k): swizzled [key][d] fp16 in KV tile plane 0
//  t=2 (v): swizzled [d][key] fp16 in KV tile plane 1
// ---------------------------------------------------------------------------
__global__ __launch_bounds__(256) void qkv_mfma_kernel(
    const ushort* __restrict__ wsu, int b0) {
  const int nT = blockIdx.x, oT = blockIdx.y, bb = blockIdx.z;
  const ushort* whi = wsu;
  const ushort* slot = wsu + (size_t)W_U16 + (size_t)bb * SLOT_U16;
  const ushort* xth = slot;
  const int oBase = oT * 64, nBase = nT * 64;

  __shared__ __align__(16) ushort Wh[2][64 * 64];
  __shared__ __align__(16) ushort Xh[2][64 * 64];

  const int tid = threadIdx.x;
  const int w = tid >> 6, l = tid & 63;
  const int lq = l & 15, lh = l >> 4;

  const int r0 = tid >> 3, g0 = tid & 7;
  const size_t srcA = (size_t)(oBase + r0) * 384 + 8 * g0;   // W rows
  const size_t srcB = (size_t)(nBase + r0) * 384 + 8 * g0;   // X rows
  const int dst0 = r0 * 64 + 8 * (g0 ^ (r0 & 7));
  const int dst1 = dst0 + 2048;                               // row+32

  f32x4 acc[4];
#pragma unroll
  for (int f = 0; f < 4; ++f) acc[f] = (f32x4){0.f, 0.f, 0.f, 0.f};

  uint4 t0, t1, t2, t3;
#define QSTAGE(c0)                                                        \
  {                                                                       \
    t0 = *(const uint4*)&whi[srcA + (c0)];                                \
    t1 = *(const uint4*)&whi[srcA + 32 * 384 + (c0)];                     \
    t2 = *(const uint4*)&xth[srcB + (c0)];                                \
    t3 = *(const uint4*)&xth[srcB + 32 * 384 + (c0)];                     \
  }
#define QCOMMIT(B)                                                        \
  {                                                                       \
    *(uint4*)&Wh[B][dst0] = t0; *(uint4*)&Wh[B][dst1] = t1;               \
    *(uint4*)&Xh[B][dst0] = t2; *(uint4*)&Xh[B][dst1] = t3;               \
  }

  QSTAGE(0)
  QCOMMIT(0)
  __syncthreads();

#pragma unroll
  for (int step = 0; step < 6; ++step) {
    const int cur = step & 1;
    if (step < 5) QSTAGE((step + 1) * 64)  // next-step loads in flight
    __builtin_amdgcn_s_setprio(1);
#pragma unroll
    for (int s = 0; s < 2; ++s) {
      const int nrow = 16 * w + lq;
      const int g = 4 * s + lh;
      f16x8 xh = *(const f16x8*)&Xh[cur][nrow * 64 + 8 * (g ^ (nrow & 7))];
#pragma unroll
      for (int f = 0; f < 4; ++f) {
        const int orow = 16 * f + lq;
        f16x8 wh_ = *(const f16x8*)&Wh[cur][orow * 64 + 8 * (g ^ (orow & 7))];
        acc[f] = __builtin_amdgcn_mfma_f32_16x16x32_f16(wh_, xh, acc[f], 0, 0, 0);
      }
    }
    __builtin_amdgcn_s_setprio(0);
    if (step < 5) {
      QCOMMIT(cur ^ 1)   // other buffer: no pre-commit barrier needed
      __syncthreads();   // commits visible before next step's reads
    }
  }

  const int t = oT % 3, head = oT / 3;
  ushort* pb = (ushort*)slot + (size_t)XT_U16 + (size_t)head * HEAD_U16;
  if (t == 0) {  // q: [n][64] fp16 (log2e folded via W)
    const int n = nBase + 16 * w + lq;
#pragma unroll
    for (int f = 0; f < 4; ++f) {
      uint2 uh;
      uh.x = (uint)f2h(acc[f][0] * WS_INV) | ((uint)f2h(acc[f][1] * WS_INV) << 16);
      uh.y = (uint)f2h(acc[f][2] * WS_INV) | ((uint)f2h(acc[f][3] * WS_INV) << 16);
      *(uint2*)&pb[(size_t)n * 64 + 16 * f + 4 * lh] = uh;
    }
  } else if (t == 1) {  // k: swizzled [key][d] fp16, KV tile plane 0
    ushort* kv = pb + (size_t)PLANE_U16 + (size_t)nT * KVTILE_U16;
    const int row = 16 * w + lq;  // key within tile
#pragma unroll
    for (int f = 0; f < 4; ++f) {
      uint2 uh;
      uh.x = (uint)f2h(acc[f][0] * WS_INV) | ((uint)f2h(acc[f][1] * WS_INV) << 16);
      uh.y = (uint)f2h(acc[f][2] * WS_INV) | ((uint)f2h(acc[f][3] * WS_INV) << 16);
      const int idx = row * 64 + 8 * ((2 * f + (lh >> 1)) ^ (row & 7)) + 4 * (lh & 1);
      *(uint2*)&kv[idx] = uh;
    }
  } else {  // v: swizzled [d][key] fp16, KV tile plane 1
    ushort* pv = pb + (size_t)PLANE_U16 + (size_t)nT * KVTILE_U16 + 4096;
    const int col = 16 * w + lq;  // key within tile
    const int cg = col >> 3, cr = col & 7;
#pragma unroll
    for (int f = 0; f < 4; ++f)
#pragma unroll
      for (int r = 0; r < 4; ++r) {
        const int row = 16 * f + 4 * lh + r;
        pv[row * 64 + 8 * (cg ^ (row & 7)) + cr] = f2h(acc[f][r] * WS_INV);
      }
  }
}

// ---------------------------------------------------------------------------
// Kernel B: single-fp16 MFMA flash attention, offset-free exp2 softmax.
// 128 queries/block as TWO 64-query tiles (n0 and n0+64).  K fragments
// hoisted into registers once per KV tile (reused by both q-tiles); V read
// from LDS per tile.  Separate Pw slices/oac/l per tile; memory fence
// between P-pack writes and P-fragment reads.  KVBLK=64, reg-staged
// prefetch, XCD-swizzled flattened grid, 4 blocks/CU (no dispatch tail).
// ---------------------------------------------------------------------------
__global__ __launch_bounds__(256, 4) void attn_mfma_kernel(
    const ushort* __restrict__ wsu, float* __restrict__ out, int b0, int nbw) {
  int wid = blockIdx.x + 18 * (blockIdx.y + 6 * blockIdx.z);
  const int nwg = 18 * 6 * nbw;
  if ((nwg & 7) == 0) {
    const int chunk = nwg >> 3;
    wid = (wid & 7) * chunk + (wid >> 3);
  }
  const int qt = wid % 18;
  const int rest = wid / 18;
  const int h = rest % 6;
  const int bb = rest / 6;
  const int b = b0 + bb;

  const ushort* pbh = wsu + (size_t)W_U16 + (size_t)bb * SLOT_U16 +
                      (size_t)XT_U16 + (size_t)h * HEAD_U16;
  const ushort* qhP = pbh;
  const char* kvG = (const char*)(pbh + (size_t)PLANE_U16);  // 36 x 16 KB
  const int n0 = qt * 128;

  __shared__ __align__(16) ushort KV[8192];       // Kh | Vh (pre-swizzled)
  __shared__ __align__(16) ushort Pw[4][2][1024]; // per-wave, per-tile P

  const int tid = threadIdx.x;
  const int w = tid >> 6;
  const int l = tid & 63;
  const int lq = l & 15;
  const int lh = l >> 4;

  // Two register-resident 64-query tiles: rows n0+16w+lq and +64.
  f16x8 qh0[2], qh1[2];
  {
    const ushort* qr = qhP + (size_t)(n0 + 16 * w + lq) * 64 + 8 * lh;
    qh0[0] = *(const f16x8*)(qr);
    qh0[1] = *(const f16x8*)(qr + 32);
    qh1[0] = *(const f16x8*)(qr + 4096);   // +64 rows * 64
    qh1[1] = *(const f16x8*)(qr + 4128);
  }

  f32x4 oac0[4], oac1[4];
#pragma unroll
  for (int i = 0; i < 4; ++i) {
    oac0[i] = (f32x4){0.f, 0.f, 0.f, 0.f};
    oac1[i] = (f32x4){0.f, 0.f, 0.f, 0.f};
  }
  float l0 = 0.f, l1 = 0.f;

  const char* gbase = kvG + w * 4096 + l * 16;
  char* lbase = (char*)&KV[0] + w * 4096 + l * 16;

  uint4 s0, s1, s2, s3;
#define ASTAGE(mt)                                                        \
  {                                                                       \
    const char* p_ = gbase + (size_t)(mt) * 16384;                        \
    s0 = *(const uint4*)(p_);                                             \
    s1 = *(const uint4*)(p_ + 1024);                                      \
    s2 = *(const uint4*)(p_ + 2048);                                      \
    s3 = *(const uint4*)(p_ + 3072);                                      \
  }
#define ACOMMIT()                                                         \
  {                                                                       \
    *(uint4*)(lbase) = s0;                                                \
    *(uint4*)(lbase + 1024) = s1;                                         \
    *(uint4*)(lbase + 2048) = s2;                                         \
    *(uint4*)(lbase + 3072) = s3;                                         \
  }

  ASTAGE(0)
  ACOMMIT()
  __syncthreads();

  const ushort* Kh = &KV[0];
  const ushort* Vh = &KV[4096];

  // Per-lane LDS offsets: rows are 16f+lq so row&7 == lq&7 for all f.
  const int rb0 = lq * 64, rb1 = (16 + lq) * 64,
            rb2 = (32 + lq) * 64, rb3 = (48 + lq) * 64;
  const int x0 = 8 * (lh ^ (lq & 7));
  const int x1 = 8 * ((4 + lh) ^ (lq & 7));
  const int pwr = lq * 64;

  for (int mt = 0; mt < 36; ++mt) {
    const bool hasNext = (mt + 1 < 36);
    if (hasNext) ASTAGE(mt + 1)  // global loads in flight during compute

    // K fragments loaded ONCE into registers, reused by both q-tiles.
    f16x8 k00 = *(const f16x8*)&Kh[rb0 + x0], k01 = *(const f16x8*)&Kh[rb0 + x1];
    f16x8 k10 = *(const f16x8*)&Kh[rb1 + x0], k11 = *(const f16x8*)&Kh[rb1 + x1];
    f16x8 k20 = *(const f16x8*)&Kh[rb2 + x0], k21 = *(const f16x8*)&Kh[rb2 + x1];
    f16x8 k30 = *(const f16x8*)&Kh[rb3 + x0], k31 = *(const f16x8*)&Kh[rb3 + x1];

    // ---- q-tile 0 ----
    {
      f32x4 st[4];
#pragma unroll
      for (int f = 0; f < 4; ++f) st[f] = (f32x4){0.f, 0.f, 0.f, 0.f};
      __builtin_amdgcn_s_setprio(1);
      st[0] = __builtin_amdgcn_mfma_f32_16x16x32_f16(k00, qh0[0], st[0], 0, 0, 0);
      st[0] = __builtin_amdgcn_mfma_f32_16x16x32_f16(k01, qh0[1], st[0], 0, 0, 0);
      st[1] = __builtin_amdgcn_mfma_f32_16x16x32_f16(k10, qh0[0], st[1], 0, 0, 0);
      st[1] = __builtin_amdgcn_mfma_f32_16x16x32_f16(k11, qh0[1], st[1], 0, 0, 0);
      st[2] = __builtin_amdgcn_mfma_f32_16x16x32_f16(k20, qh0[0], st[2], 0, 0, 0);
      st[2] = __builtin_amdgcn_mfma_f32_16x16x32_f16(k21, qh0[1], st[2], 0, 0, 0);
      st[3] = __builtin_amdgcn_mfma_f32_16x16x32_f16(k30, qh0[0], st[3], 0, 0, 0);
      st[3] = __builtin_amdgcn_mfma_f32_16x16x32_f16(k31, qh0[1], st[3], 0, 0, 0);
      __builtin_amdgcn_s_setprio(0);
#pragma unroll
      for (int f = 0; f < 4; ++f)
#pragma unroll
        for (int r = 0; r < 4; ++r) {
          st[f][r] = exp2_fast(st[f][r]);
          l0 += st[f][r];
        }
      ushort* pw = &Pw[w][0][0];
#pragma unroll
      for (int f = 0; f < 4; ++f) {
        uint2 uu;
        uu.x = cvt_pk_f16(st[f][0], st[f][1]);
        uu.y = cvt_pk_f16(st[f][2], st[f][3]);
        int ui = lq * 64 + 8 * ((2 * f + (lh >> 1)) ^ (lq & 7)) + 4 * (lh & 1);
        *(uint2*)&pw[ui] = uu;
      }
      asm volatile("" ::: "memory");  // pin LDS write->read order
      f16x8 p0 = *(const f16x8*)&pw[pwr + x0];
      f16x8 p1 = *(const f16x8*)&pw[pwr + x1];
      __builtin_amdgcn_s_setprio(1);
      oac0[0] = __builtin_amdgcn_mfma_f32_16x16x32_f16(*(const f16x8*)&Vh[rb0 + x0], p0, oac0[0], 0, 0, 0);
      oac0[0] = __builtin_amdgcn_mfma_f32_16x16x32_f16(*(const f16x8*)&Vh[rb0 + x1], p1, oac0[0], 0, 0, 0);
      oac0[1] = __builtin_amdgcn_mfma_f32_16x16x32_f16(*(const f16x8*)&Vh[rb1 + x0], p0, oac0[1], 0, 0, 0);
      oac0[1] = __builtin_amdgcn_mfma_f32_16x16x32_f16(*(const f16x8*)&Vh[rb1 + x1], p1, oac0[1], 0, 0, 0);
      oac0[2] = __builtin_amdgcn_mfma_f32_16x16x32_f16(*(const f16x8*)&Vh[rb2 + x0], p0, oac0[2], 0, 0, 0);
      oac0[2] = __builtin_amdgcn_mfma_f32_16x16x32_f16(*(const f16x8*)&Vh[rb2 + x1], p1, oac0[2], 0, 0, 0);
      oac0[3] = __builtin_amdgcn_mfma_f32_16x16x32_f16(*(const f16x8*)&Vh[rb3 + x0], p0, oac0[3], 0, 0, 0);
      oac0[3] = __builtin_amdgcn_mfma_f32_16x16x32_f16(*(const f16x8*)&Vh[rb3 + x1], p1, oac0[3], 0, 0, 0);
      __builtin_amdgcn_s_setprio(0);
    }

    // ---- q-tile 1 (same K registers, separate Pw slice) ----
    {
      f32x4 st[4];
#pragma unroll
      for (int f = 0; f < 4; ++f) st[f] = (f32x4){0.f, 0.f, 0.f, 0.f};
      __builtin_amdgcn_s_setprio(1);
      st[0] = __builtin_amdgcn_mfma_f32_16x16x32_f16(k00, qh1[0], st[0], 0, 0, 0);
      st[0] = __builtin_amdgcn_mfma_f32_16x16x32_f16(k01, qh1[1], st[0], 0, 0, 0);
      st[1] = __builtin_amdgcn_mfma_f32_16x16x32_f16(k10, qh1[0], st[1], 0, 0, 0);
      st[1] = __builtin_amdgcn_mfma_f32_16x16x32_f16(k11, qh1[1], st[1], 0, 0, 0);
      st[2] = __builtin_amdgcn_mfma_f32_16x16x32_f16(k20, qh1[0], st[2], 0, 0, 0);
      st[2] = __builtin_amdgcn_mfma_f32_16x16x32_f16(k21, qh1[1], st[2], 0, 0, 0);
      st[3] = __builtin_amdgcn_mfma_f32_16x16x32_f16(k30, qh1[0], st[3], 0, 0, 0);
      st[3] = __builtin_amdgcn_mfma_f32_16x16x32_f16(k31, qh1[1], st[3], 0, 0, 0);
      __builtin_amdgcn_s_setprio(0);
#pragma unroll
      for (int f = 0; f < 4; ++f)
#pragma unroll
        for (int r = 0; r < 4; ++r) {
          st[f][r] = exp2_fast(st[f][r]);
          l1 += st[f][r];
        }
      ushort* pw = &Pw[w][1][0];
#pragma unroll
      for (int f = 0; f < 4; ++f) {
        uint2 uu;
        uu.x = cvt_pk_f16(st[f][0], st[f][1]);
        uu.y = cvt_pk_f16(st[f][2], st[f][3]);
        int ui = lq * 64 + 8 * ((2 * f + (lh >> 1)) ^ (lq & 7)) + 4 * (lh & 1);
        *(uint2*)&pw[ui] = uu;
      }
      asm volatile("" ::: "memory");  // pin LDS write->read order
      f16x8 p0 = *(const f16x8*)&pw[pwr + x0];
      f16x8 p1 = *(const f16x8*)&pw[pwr + x1];
      __builtin_amdgcn_s_setprio(1);
      oac1[0] = __builtin_amdgcn_mfma_f32_16x16x32_f16(*(const f16x8*)&Vh[rb0 + x0], p0, oac1[0], 0, 0, 0);
      oac1[0] = __builtin_amdgcn_mfma_f32_16x16x32_f16(*(const f16x8*)&Vh[rb0 + x1], p1, oac1[0], 0, 0, 0);
      oac1[1] = __builtin_amdgcn_mfma_f32_16x16x32_f16(*(const f16x8*)&Vh[rb1 + x0], p0, oac1[1], 0, 0, 0);
      oac1[1] = __builtin_amdgcn_mfma_f32_16x16x32_f16(*(const f16x8*)&Vh[rb1 + x1], p1, oac1[1], 0, 0, 0);
      oac1[2] = __builtin_amdgcn_mfma_f32_16x16x32_f16(*(const f16x8*)&Vh[rb2 + x0], p0, oac1[2], 0, 0, 0);
      oac1[2] = __builtin_amdgcn_mfma_f32_16x16x32_f16(*(const f16x8*)&Vh[rb2 + x1], p1, oac1[2], 0, 0, 0);
      oac1[3] = __builtin_amdgcn_mfma_f32_16x16x32_f16(*(const f16x8*)&Vh[rb3 + x0], p0, oac1[3], 0, 0, 0);
      oac1[3] = __builtin_amdgcn_mfma_f32_16x16x32_f16(*(const f16x8*)&Vh[rb3 + x1], p1, oac1[3], 0, 0, 0);
      __builtin_amdgcn_s_setprio(0);
    }

    if (hasNext) {
      __syncthreads();   // all waves done reading KV
      ACOMMIT()          // vmcnt wait on s0..s3 sources is free by now
      __syncthreads();   // next tile ready
    }
  }

  // Cross-lane denominator reduces (partners at lane^16, lane^32).
  l0 += __shfl_xor(l0, 16);
  l0 += __shfl_xor(l0, 32);
  l1 += __shfl_xor(l1, 16);
  l1 += __shfl_xor(l1, 32);
  const float inv0 = 1.f / l0, inv1 = 1.f / l1;

  const int ncol0 = n0 + 16 * w + lq;
#pragma unroll
  for (int fd = 0; fd < 4; ++fd)
#pragma unroll
    for (int r = 0; r < 4; ++r) {
      const size_t rowOff = ((size_t)b * 384 + h * 64 + 16 * fd + 4 * lh + r) * NTOK;
      out[rowOff + ncol0] = oac0[fd][r] * inv0;
      out[rowOff + ncol0 + 64] = oac1[fd][r] * inv1;
    }
}

extern "C" void kernel_launch(void* const* d_in, const int* in_sizes, int n_in,
                              void* d_out, int out_size, void* d_ws,
                              size_t ws_size, hipStream_t stream) {
  const float* x = (const float*)d_in[0];
  const float* w = (const float*)d_in[1];
  float* out = (float*)d_out;
  ushort* wsu = (ushort*)d_ws;

  int nbFit = (int)((ws_size - WBYTES) / SLOT_BYTES);
  if (nbFit < 1) nbFit = 1;
  if (nbFit > NB) nbFit = NB;

  hipLaunchKernelGGL(prep_w_kernel, dim3(432), dim3(256), 0, stream, w, wsu);
  for (int b0 = 0; b0 < NB; b0 += nbFit) {
    int nb = NB - b0;
    if (nb > nbFit) nb = nbFit;
    hipLaunchKernelGGL(prep_x_kernel, dim3(48, 6, nb), dim3(256), 0, stream,
                       x, wsu, b0);
    hipLaunchKernelGGL(qkv_mfma_kernel, dim3(36, 18, nb), dim3(256), 0, stream,
                       wsu, b0);
    hipLaunchKernelGGL(attn_mfma_kernel, dim3(18, 6, nb), dim3(256), 0, stream,
                       wsu, out, b0, nb);
  }
}

// Round 21
// 146.219 us; speedup vs baseline: 2.0428x; 2.0428x over previous
//
#include <hip/hip_runtime.h>

// B=8, C=384, 96x96 stride-2 -> 48x48, N=2304 tokens.
// qkv = W(1152x384) @ xs(384xN); 6 heads x (q,k,v) of 64 dims.
// attn = softmax(q^T k); out[d][n] = sum_m v[d][m] P[n][m].
// Single-fp16 MFMA pipeline, offset-free exp2 softmax.
// Attention: 128 queries/block as two 64-query tiles.  K fragments are
// loaded ONCE per KV tile into registers (32 VGPR) and reused by both
// q-tiles; V is read from LDS per tile.  __launch_bounds__(256,3) — both
// tighter (256,4) and full K+V hoist spill (WRITE_SIZE canary).  Compiler
// memory fence between P-pack LDS writes and P-fragment reads.

#define NTOK 2304
#define NB 8
#define W_U16 (1152 * 384)             // W fp16 plane (single)
#define XT_U16 (NTOK * 384)            // xsT fp16 plane (single)
#define PLANE_U16 (NTOK * 64)          // one qkv fp16 plane (147456)
#define KVTILE_U16 8192                // Kh(4096) + V(4096) per 64-key tile
#define HEAD_U16 (PLANE_U16 + 36 * KVTILE_U16)   // Qh + 36 KV tiles
#define SLOT_U16 (XT_U16 + 6 * HEAD_U16)
#define SLOT_BYTES ((size_t)SLOT_U16 * 2)   // 7.08 MB / batch
#define WBYTES ((size_t)W_U16 * 2)          // 0.88 MB
#define LOG2E 1.4426950408889634f
#define WSCALE 1024.0f
#define WS_INV (1.0f / 1024.0f)

typedef __attribute__((ext_vector_type(8))) _Float16 f16x8;
typedef __attribute__((ext_vector_type(4))) float f32x4;

__device__ __forceinline__ ushort f2h(float f) {
  union { _Float16 h; ushort u; } v; v.h = (_Float16)f; return v.u;
}
__device__ __forceinline__ uint cvt_pk_f16(float lo, float hi) {
  uint r;
  asm("v_cvt_pkrtz_f16_f32 %0, %1, %2" : "=v"(r) : "v"(lo), "v"(hi));
  return r;
}
__device__ __forceinline__ float exp2_fast(float x) {
  float r;
  asm("v_exp_f32 %0, %1" : "=v"(r) : "v"(x));
  return r;
}

// ---------------------------------------------------------------------------
// Kernel W: 1024*W -> single fp16 plane; q-rows also carry log2(e).
// ---------------------------------------------------------------------------
__global__ __launch_bounds__(256) void prep_w_kernel(
    const float* __restrict__ w, ushort* __restrict__ wsu) {
  const int idx4 = blockIdx.x * 256 + threadIdx.x;  // 110592 total
  const int o = idx4 / 96;                          // W row
  const float scale = (((o % 192) < 64) ? LOG2E : 1.0f) * WSCALE;
  float4 v = *(const float4*)&w[(size_t)idx4 * 4];
  uint2 uh;
  uh.x = (uint)f2h(v.x * scale) | ((uint)f2h(v.y * scale) << 16);
  uh.y = (uint)f2h(v.z * scale) | ((uint)f2h(v.w * scale) << 16);
  *(uint2*)&wsu[(size_t)idx4 * 4] = uh;
}

// ---------------------------------------------------------------------------
// Kernel X: subsample + transpose x -> xsT[n][c] single fp16 plane.
// ---------------------------------------------------------------------------
__global__ __launch_bounds__(256) void prep_x_kernel(
    const float* __restrict__ x, ushort* __restrict__ wsu, int b0) {
  const int hh = blockIdx.x, cc = blockIdx.y, bb = blockIdx.z;
  const int b = b0 + bb;
  const int c0 = cc * 64;
  ushort* xth = wsu + (size_t)W_U16 + (size_t)bb * SLOT_U16;
  const float* xb = x + ((size_t)b * 384 + c0) * 9216 + 192 * hh;

  __shared__ float T[64][49];
  const int tid = threadIdx.x;
#pragma unroll
  for (int i = 0; i < 8; ++i) {
    int idx = tid + 256 * i;
    int cl = idx >> 5, q = idx & 31;
    if (q < 24) {
      float4 v = *(const float4*)&xb[(size_t)cl * 9216 + 4 * q];
      T[cl][2 * q] = v.x;
      T[cl][2 * q + 1] = v.z;
    }
  }
  __syncthreads();
#pragma unroll
  for (int i = 0; i < 2; ++i) {
    int item = tid + 256 * i;
    if (item < 384) {
      int ww = item >> 3, cg = item & 7;
      int n = hh * 48 + ww;
      uint uh[4];
#pragma unroll
      for (int p = 0; p < 4; ++p) {
        float f0 = T[8 * cg + 2 * p][ww], f1 = T[8 * cg + 2 * p + 1][ww];
        uh[p] = (uint)f2h(f0) | ((uint)f2h(f1) << 16);
      }
      uint4 H = {uh[0], uh[1], uh[2], uh[3]};
      *(uint4*)&xth[(size_t)n * 384 + c0 + 8 * cg] = H;
    }
  }
}

// ---------------------------------------------------------------------------
// Kernel G: single-fp16 MFMA projection GEMM (8 MFMA/K-step), reg-prefetch
// + double-buffered LDS (one barrier per K-step).  Epilogue (acc * 1/1024)
// writes attention-ready layouts:
//  t=0 (q): [n][64] fp16 plane
//  t=1 (k): swizzled [key][d] fp16 in KV tile plane 0
//  t=2 (v): swizzled [d][key] fp16 in KV tile plane 1
// ---------------------------------------------------------------------------
__global__ __launch_bounds__(256) void qkv_mfma_kernel(
    const ushort* __restrict__ wsu, int b0) {
  const int nT = blockIdx.x, oT = blockIdx.y, bb = blockIdx.z;
  const ushort* whi = wsu;
  const ushort* slot = wsu + (size_t)W_U16 + (size_t)bb * SLOT_U16;
  const ushort* xth = slot;
  const int oBase = oT * 64, nBase = nT * 64;

  __shared__ __align__(16) ushort Wh[2][64 * 64];
  __shared__ __align__(16) ushort Xh[2][64 * 64];

  const int tid = threadIdx.x;
  const int w = tid >> 6, l = tid & 63;
  const int lq = l & 15, lh = l >> 4;

  const int r0 = tid >> 3, g0 = tid & 7;
  const size_t srcA = (size_t)(oBase + r0) * 384 + 8 * g0;   // W rows
  const size_t srcB = (size_t)(nBase + r0) * 384 + 8 * g0;   // X rows
  const int dst0 = r0 * 64 + 8 * (g0 ^ (r0 & 7));
  const int dst1 = dst0 + 2048;                               // row+32

  f32x4 acc[4];
#pragma unroll
  for (int f = 0; f < 4; ++f) acc[f] = (f32x4){0.f, 0.f, 0.f, 0.f};

  uint4 t0, t1, t2, t3;
#define QSTAGE(c0)                                                        \
  {                                                                       \
    t0 = *(const uint4*)&whi[srcA + (c0)];                                \
    t1 = *(const uint4*)&whi[srcA + 32 * 384 + (c0)];                     \
    t2 = *(const uint4*)&xth[srcB + (c0)];                                \
    t3 = *(const uint4*)&xth[srcB + 32 * 384 + (c0)];                     \
  }
#define QCOMMIT(B)                                                        \
  {                                                                       \
    *(uint4*)&Wh[B][dst0] = t0; *(uint4*)&Wh[B][dst1] = t1;               \
    *(uint4*)&Xh[B][dst0] = t2; *(uint4*)&Xh[B][dst1] = t3;               \
  }

  QSTAGE(0)
  QCOMMIT(0)
  __syncthreads();

#pragma unroll
  for (int step = 0; step < 6; ++step) {
    const int cur = step & 1;
    if (step < 5) QSTAGE((step + 1) * 64)  // next-step loads in flight
    __builtin_amdgcn_s_setprio(1);
#pragma unroll
    for (int s = 0; s < 2; ++s) {
      const int nrow = 16 * w + lq;
      const int g = 4 * s + lh;
      f16x8 xh = *(const f16x8*)&Xh[cur][nrow * 64 + 8 * (g ^ (nrow & 7))];
#pragma unroll
      for (int f = 0; f < 4; ++f) {
        const int orow = 16 * f + lq;
        f16x8 wh_ = *(const f16x8*)&Wh[cur][orow * 64 + 8 * (g ^ (orow & 7))];
        acc[f] = __builtin_amdgcn_mfma_f32_16x16x32_f16(wh_, xh, acc[f], 0, 0, 0);
      }
    }
    __builtin_amdgcn_s_setprio(0);
    if (step < 5) {
      QCOMMIT(cur ^ 1)   // other buffer: no pre-commit barrier needed
      __syncthreads();   // commits visible before next step's reads
    }
  }

  const int t = oT % 3, head = oT / 3;
  ushort* pb = (ushort*)slot + (size_t)XT_U16 + (size_t)head * HEAD_U16;
  if (t == 0) {  // q: [n][64] fp16 (log2e folded via W)
    const int n = nBase + 16 * w + lq;
#pragma unroll
    for (int f = 0; f < 4; ++f) {
      uint2 uh;
      uh.x = (uint)f2h(acc[f][0] * WS_INV) | ((uint)f2h(acc[f][1] * WS_INV) << 16);
      uh.y = (uint)f2h(acc[f][2] * WS_INV) | ((uint)f2h(acc[f][3] * WS_INV) << 16);
      *(uint2*)&pb[(size_t)n * 64 + 16 * f + 4 * lh] = uh;
    }
  } else if (t == 1) {  // k: swizzled [key][d] fp16, KV tile plane 0
    ushort* kv = pb + (size_t)PLANE_U16 + (size_t)nT * KVTILE_U16;
    const int row = 16 * w + lq;  // key within tile
#pragma unroll
    for (int f = 0; f < 4; ++f) {
      uint2 uh;
      uh.x = (uint)f2h(acc[f][0] * WS_INV) | ((uint)f2h(acc[f][1] * WS_INV) << 16);
      uh.y = (uint)f2h(acc[f][2] * WS_INV) | ((uint)f2h(acc[f][3] * WS_INV) << 16);
      const int idx = row * 64 + 8 * ((2 * f + (lh >> 1)) ^ (row & 7)) + 4 * (lh & 1);
      *(uint2*)&kv[idx] = uh;
    }
  } else {  // v: swizzled [d][key] fp16, KV tile plane 1
    ushort* pv = pb + (size_t)PLANE_U16 + (size_t)nT * KVTILE_U16 + 4096;
    const int col = 16 * w + lq;  // key within tile
    const int cg = col >> 3, cr = col & 7;
#pragma unroll
    for (int f = 0; f < 4; ++f)
#pragma unroll
      for (int r = 0; r < 4; ++r) {
        const int row = 16 * f + 4 * lh + r;
        pv[row * 64 + 8 * (cg ^ (row & 7)) + cr] = f2h(acc[f][r] * WS_INV);
      }
  }
}

// ---------------------------------------------------------------------------
// Kernel B: single-fp16 MFMA flash attention, offset-free exp2 softmax.
// 128 queries/block as TWO 64-query tiles (n0 and n0+64).  K fragments
// hoisted into registers once per KV tile (reused by both q-tiles); V read
// from LDS per tile.  Separate Pw slices/oac/l per tile; memory fence
// between P-pack writes and P-fragment reads.  KVBLK=64, reg-staged
// prefetch, XCD-swizzled flattened grid.
// ---------------------------------------------------------------------------
__global__ __launch_bounds__(256, 3) void attn_mfma_kernel(
    const ushort* __restrict__ wsu, float* __restrict__ out, int b0, int nbw) {
  int wid = blockIdx.x + 18 * (blockIdx.y + 6 * blockIdx.z);
  const int nwg = 18 * 6 * nbw;
  if ((nwg & 7) == 0) {
    const int chunk = nwg >> 3;
    wid = (wid & 7) * chunk + (wid >> 3);
  }
  const int qt = wid % 18;
  const int rest = wid / 18;
  const int h = rest % 6;
  const int bb = rest / 6;
  const int b = b0 + bb;

  const ushort* pbh = wsu + (size_t)W_U16 + (size_t)bb * SLOT_U16 +
                      (size_t)XT_U16 + (size_t)h * HEAD_U16;
  const ushort* qhP = pbh;
  const char* kvG = (const char*)(pbh + (size_t)PLANE_U16);  // 36 x 16 KB
  const int n0 = qt * 128;

  __shared__ __align__(16) ushort KV[8192];       // Kh | Vh (pre-swizzled)
  __shared__ __align__(16) ushort Pw[4][2][1024]; // per-wave, per-tile P

  const int tid = threadIdx.x;
  const int w = tid >> 6;
  const int l = tid & 63;
  const int lq = l & 15;
  const int lh = l >> 4;

  // Two register-resident 64-query tiles: rows n0+16w+lq and +64.
  f16x8 qh0[2], qh1[2];
  {
    const ushort* qr = qhP + (size_t)(n0 + 16 * w + lq) * 64 + 8 * lh;
    qh0[0] = *(const f16x8*)(qr);
    qh0[1] = *(const f16x8*)(qr + 32);
    qh1[0] = *(const f16x8*)(qr + 4096);   // +64 rows * 64
    qh1[1] = *(const f16x8*)(qr + 4128);
  }

  f32x4 oac0[4], oac1[4];
#pragma unroll
  for (int i = 0; i < 4; ++i) {
    oac0[i] = (f32x4){0.f, 0.f, 0.f, 0.f};
    oac1[i] = (f32x4){0.f, 0.f, 0.f, 0.f};
  }
  float l0 = 0.f, l1 = 0.f;

  const char* gbase = kvG + w * 4096 + l * 16;
  char* lbase = (char*)&KV[0] + w * 4096 + l * 16;

  uint4 s0, s1, s2, s3;
#define ASTAGE(mt)                                                        \
  {                                                                       \
    const char* p_ = gbase + (size_t)(mt) * 16384;                        \
    s0 = *(const uint4*)(p_);                                             \
    s1 = *(const uint4*)(p_ + 1024);                                      \
    s2 = *(const uint4*)(p_ + 2048);                                      \
    s3 = *(const uint4*)(p_ + 3072);                                      \
  }
#define ACOMMIT()                                                         \
  {                                                                       \
    *(uint4*)(lbase) = s0;                                                \
    *(uint4*)(lbase + 1024) = s1;                                         \
    *(uint4*)(lbase + 2048) = s2;                                         \
    *(uint4*)(lbase + 3072) = s3;                                         \
  }

  ASTAGE(0)
  ACOMMIT()
  __syncthreads();

  const ushort* Kh = &KV[0];
  const ushort* Vh = &KV[4096];

  // Per-lane LDS offsets: rows are 16f+lq so row&7 == lq&7 for all f.
  const int rb0 = lq * 64, rb1 = (16 + lq) * 64,
            rb2 = (32 + lq) * 64, rb3 = (48 + lq) * 64;
  const int x0 = 8 * (lh ^ (lq & 7));
  const int x1 = 8 * ((4 + lh) ^ (lq & 7));
  const int pwr = lq * 64;

  for (int mt = 0; mt < 36; ++mt) {
    const bool hasNext = (mt + 1 < 36);
    if (hasNext) ASTAGE(mt + 1)  // global loads in flight during compute

    // K fragments loaded ONCE into registers, reused by both q-tiles.
    f16x8 k00 = *(const f16x8*)&Kh[rb0 + x0], k01 = *(const f16x8*)&Kh[rb0 + x1];
    f16x8 k10 = *(const f16x8*)&Kh[rb1 + x0], k11 = *(const f16x8*)&Kh[rb1 + x1];
    f16x8 k20 = *(const f16x8*)&Kh[rb2 + x0], k21 = *(const f16x8*)&Kh[rb2 + x1];
    f16x8 k30 = *(const f16x8*)&Kh[rb3 + x0], k31 = *(const f16x8*)&Kh[rb3 + x1];

    // ---- q-tile 0 ----
    {
      f32x4 st[4];
#pragma unroll
      for (int f = 0; f < 4; ++f) st[f] = (f32x4){0.f, 0.f, 0.f, 0.f};
      __builtin_amdgcn_s_setprio(1);
      st[0] = __builtin_amdgcn_mfma_f32_16x16x32_f16(k00, qh0[0], st[0], 0, 0, 0);
      st[0] = __builtin_amdgcn_mfma_f32_16x16x32_f16(k01, qh0[1], st[0], 0, 0, 0);
      st[1] = __builtin_amdgcn_mfma_f32_16x16x32_f16(k10, qh0[0], st[1], 0, 0, 0);
      st[1] = __builtin_amdgcn_mfma_f32_16x16x32_f16(k11, qh0[1], st[1], 0, 0, 0);
      st[2] = __builtin_amdgcn_mfma_f32_16x16x32_f16(k20, qh0[0], st[2], 0, 0, 0);
      st[2] = __builtin_amdgcn_mfma_f32_16x16x32_f16(k21, qh0[1], st[2], 0, 0, 0);
      st[3] = __builtin_amdgcn_mfma_f32_16x16x32_f16(k30, qh0[0], st[3], 0, 0, 0);
      st[3] = __builtin_amdgcn_mfma_f32_16x16x32_f16(k31, qh0[1], st[3], 0, 0, 0);
      __builtin_amdgcn_s_setprio(0);
#pragma unroll
      for (int f = 0; f < 4; ++f)
#pragma unroll
        for (int r = 0; r < 4; ++r) {
          st[f][r] = exp2_fast(st[f][r]);
          l0 += st[f][r];
        }
      ushort* pw = &Pw[w][0][0];
#pragma unroll
      for (int f = 0; f < 4; ++f) {
        uint2 uu;
        uu.x = cvt_pk_f16(st[f][0], st[f][1]);
        uu.y = cvt_pk_f16(st[f][2], st[f][3]);
        int ui = lq * 64 + 8 * ((2 * f + (lh >> 1)) ^ (lq & 7)) + 4 * (lh & 1);
        *(uint2*)&pw[ui] = uu;
      }
      asm volatile("" ::: "memory");  // pin LDS write->read order
      f16x8 p0 = *(const f16x8*)&pw[pwr + x0];
      f16x8 p1 = *(const f16x8*)&pw[pwr + x1];
      __builtin_amdgcn_s_setprio(1);
      oac0[0] = __builtin_amdgcn_mfma_f32_16x16x32_f16(*(const f16x8*)&Vh[rb0 + x0], p0, oac0[0], 0, 0, 0);
      oac0[0] = __builtin_amdgcn_mfma_f32_16x16x32_f16(*(const f16x8*)&Vh[rb0 + x1], p1, oac0[0], 0, 0, 0);
      oac0[1] = __builtin_amdgcn_mfma_f32_16x16x32_f16(*(const f16x8*)&Vh[rb1 + x0], p0, oac0[1], 0, 0, 0);
      oac0[1] = __builtin_amdgcn_mfma_f32_16x16x32_f16(*(const f16x8*)&Vh[rb1 + x1], p1, oac0[1], 0, 0, 0);
      oac0[2] = __builtin_amdgcn_mfma_f32_16x16x32_f16(*(const f16x8*)&Vh[rb2 + x0], p0, oac0[2], 0, 0, 0);
      oac0[2] = __builtin_amdgcn_mfma_f32_16x16x32_f16(*(const f16x8*)&Vh[rb2 + x1], p1, oac0[2], 0, 0, 0);
      oac0[3] = __builtin_amdgcn_mfma_f32_16x16x32_f16(*(const f16x8*)&Vh[rb3 + x0], p0, oac0[3], 0, 0, 0);
      oac0[3] = __builtin_amdgcn_mfma_f32_16x16x32_f16(*(const f16x8*)&Vh[rb3 + x1], p1, oac0[3], 0, 0, 0);
      __builtin_amdgcn_s_setprio(0);
    }

    // ---- q-tile 1 (same K registers, separate Pw slice) ----
    {
      f32x4 st[4];
#pragma unroll
      for (int f = 0; f < 4; ++f) st[f] = (f32x4){0.f, 0.f, 0.f, 0.f};
      __builtin_amdgcn_s_setprio(1);
      st[0] = __builtin_amdgcn_mfma_f32_16x16x32_f16(k00, qh1[0], st[0], 0, 0, 0);
      st[0] = __builtin_amdgcn_mfma_f32_16x16x32_f16(k01, qh1[1], st[0], 0, 0, 0);
      st[1] = __builtin_amdgcn_mfma_f32_16x16x32_f16(k10, qh1[0], st[1], 0, 0, 0);
      st[1] = __builtin_amdgcn_mfma_f32_16x16x32_f16(k11, qh1[1], st[1], 0, 0, 0);
      st[2] = __builtin_amdgcn_mfma_f32_16x16x32_f16(k20, qh1[0], st[2], 0, 0, 0);
      st[2] = __builtin_amdgcn_mfma_f32_16x16x32_f16(k21, qh1[1], st[2], 0, 0, 0);
      st[3] = __builtin_amdgcn_mfma_f32_16x16x32_f16(k30, qh1[0], st[3], 0, 0, 0);
      st[3] = __builtin_amdgcn_mfma_f32_16x16x32_f16(k31, qh1[1], st[3], 0, 0, 0);
      __builtin_amdgcn_s_setprio(0);
#pragma unroll
      for (int f = 0; f < 4; ++f)
#pragma unroll
        for (int r = 0; r < 4; ++r) {
          st[f][r] = exp2_fast(st[f][r]);
          l1 += st[f][r];
        }
      ushort* pw = &Pw[w][1][0];
#pragma unroll
      for (int f = 0; f < 4; ++f) {
        uint2 uu;
        uu.x = cvt_pk_f16(st[f][0], st[f][1]);
        uu.y = cvt_pk_f16(st[f][2], st[f][3]);
        int ui = lq * 64 + 8 * ((2 * f + (lh >> 1)) ^ (lq & 7)) + 4 * (lh & 1);
        *(uint2*)&pw[ui] = uu;
      }
      asm volatile("" ::: "memory");  // pin LDS write->read order
      f16x8 p0 = *(const f16x8*)&pw[pwr + x0];
      f16x8 p1 = *(const f16x8*)&pw[pwr + x1];
      __builtin_amdgcn_s_setprio(1);
      oac1[0] = __builtin_amdgcn_mfma_f32_16x16x32_f16(*(const f16x8*)&Vh[rb0 + x0], p0, oac1[0], 0, 0, 0);
      oac1[0] = __builtin_amdgcn_mfma_f32_16x16x32_f16(*(const f16x8*)&Vh[rb0 + x1], p1, oac1[0], 0, 0, 0);
      oac1[1] = __builtin_amdgcn_mfma_f32_16x16x32_f16(*(const f16x8*)&Vh[rb1 + x0], p0, oac1[1], 0, 0, 0);
      oac1[1] = __builtin_amdgcn_mfma_f32_16x16x32_f16(*(const f16x8*)&Vh[rb1 + x1], p1, oac1[1], 0, 0, 0);
      oac1[2] = __builtin_amdgcn_mfma_f32_16x16x32_f16(*(const f16x8*)&Vh[rb2 + x0], p0, oac1[2], 0, 0, 0);
      oac1[2] = __builtin_amdgcn_mfma_f32_16x16x32_f16(*(const f16x8*)&Vh[rb2 + x1], p1, oac1[2], 0, 0, 0);
      oac1[3] = __builtin_amdgcn_mfma_f32_16x16x32_f16(*(const f16x8*)&Vh[rb3 + x0], p0, oac1[3], 0, 0, 0);
      oac1[3] = __builtin_amdgcn_mfma_f32_16x16x32_f16(*(const f16x8*)&Vh[rb3 + x1], p1, oac1[3], 0, 0, 0);
      __builtin_amdgcn_s_setprio(0);
    }

    if (hasNext) {
      __syncthreads();   // all waves done reading KV
      ACOMMIT()          // vmcnt wait on s0..s3 sources is free by now
      __syncthreads();   // next tile ready
    }
  }

  // Cross-lane denominator reduces (partners at lane^16, lane^32).
  l0 += __shfl_xor(l0, 16);
  l0 += __shfl_xor(l0, 32);
  l1 += __shfl_xor(l1, 16);
  l1 += __shfl_xor(l1, 32);
  const float inv0 = 1.f / l0, inv1 = 1.f / l1;

  const int ncol0 = n0 + 16 * w + lq;
#pragma unroll
  for (int fd = 0; fd < 4; ++fd)
#pragma unroll
    for (int r = 0; r < 4; ++r) {
      const size_t rowOff = ((size_t)b * 384 + h * 64 + 16 * fd + 4 * lh + r) * NTOK;
      out[rowOff + ncol0] = oac0[fd][r] * inv0;
      out[rowOff + ncol0 + 64] = oac1[fd][r] * inv1;
    }
}

extern "C" void kernel_launch(void* const* d_in, const int* in_sizes, int n_in,
                              void* d_out, int out_size, void* d_ws,
                              size_t ws_size, hipStream_t stream) {
  const float* x = (const float*)d_in[0];
  const float* w = (const float*)d_in[1];
  float* out = (float*)d_out;
  ushort* wsu = (ushort*)d_ws;

  int nbFit = (int)((ws_size - WBYTES) / SLOT_BYTES);
  if (nbFit < 1) nbFit = 1;
  if (nbFit > NB) nbFit = NB;

  hipLaunchKernelGGL(prep_w_kernel, dim3(432), dim3(256), 0, stream, w, wsu);
  for (int b0 = 0; b0 < NB; b0 += nbFit) {
    int nb = NB - b0;
    if (nb > nbFit) nb = nbFit;
    hipLaunchKernelGGL(prep_x_kernel, dim3(48, 6, nb), dim3(256), 0, stream,
                       x, wsu, b0);
    hipLaunchKernelGGL(qkv_mfma_kernel, dim3(36, 18, nb), dim3(256), 0, stream,
                       wsu, b0);
    hipLaunchKernelGGL(attn_mfma_kernel, dim3(18, 6, nb), dim3(256), 0, stream,
                       wsu, out, b0, nb);
  }
}